// Round 9
// baseline (234.181 us; speedup 1.0000x reference)
//
#include <hip/hip_runtime.h>

// BiCutLoss: output [B,L,2] f32, labels [B,L] i32 -> scalar f32.
// Per row: cut = last j with out1 <= out0 (else L); loss = sum_{j<cut} out1*r1 / B.
// r1 = (label==1) ? -3.6/log2(j+2) : 0.065.
//
// Rounds 3-8: four structurally different one-block-per-row kernels all sit
// at 77-89us = 2.5 TB/s delivered reads (fill kernel: 6.9 TB/s writes).
// This round removes ALL shared structure: chunk-parallel K1 with zero
// barriers / zero LDS / wave-autonomous records, then a tiny per-row combine
// (K2) using the decomposition  sum_{j<cut} = sum(full 256-elem waves below
// cut) + boundary micro-chunk re-read.

#define LROW 4096
#define BROW 4096
#define ALPHA_R 0.065f  // alpha * 0.1

__device__ __forceinline__ float reward(int lab, int jl) {
    // -3.6/log2(j+2) via v_log_f32 + v_rcp_f32 (rel err ~1e-6 vs 2.8e-3 thr)
    const float pr = -3.6f * __builtin_amdgcn_rcpf(__log2f((float)jl + 2.0f));
    return (lab == 1) ? pr : ALPHA_R;
}

// K1: 16384 blocks x 256 thr. Block b covers elements [b*1024, b*1024+1024).
// Each wave (256 elements) writes one record {row-local zmax, full sum}.
// No barriers, no LDS, no block reduce.
__global__ __launch_bounds__(256) void bicut_k1(
    const float* __restrict__ out,
    const int* __restrict__ labels,
    int2* __restrict__ recs) {
    const int b = blockIdx.x;
    const int t = threadIdx.x;
    const int e0 = (b << 10) + (t << 2);  // global element index, 4 per thread
    const float4* o4 = reinterpret_cast<const float4*>(out);
    const int4* l4 = reinterpret_cast<const int4*>(labels);

    const float4 a = o4[e0 >> 1];        // elements e0, e0+1 (ch0,ch1 pairs)
    const float4 c = o4[(e0 >> 1) + 1];  // elements e0+2, e0+3
    const int4 lb = l4[e0 >> 2];

    const int jl = e0 & (LROW - 1);  // row-local position
    int zm = -1;                     // row-local last index with temp==0
    if (!(a.y > a.x)) zm = jl;
    if (!(a.w > a.z)) zm = jl + 1;
    if (!(c.y > c.x)) zm = jl + 2;
    if (!(c.w > c.z)) zm = jl + 3;

    float s = a.y * reward(lb.x, jl)
            + a.w * reward(lb.y, jl + 1)
            + c.y * reward(lb.z, jl + 2)
            + c.w * reward(lb.w, jl + 3);

#pragma unroll
    for (int off = 32; off; off >>= 1) {
        zm = max(zm, __shfl_down(zm, off));
        s += __shfl_down(s, off);
    }
    if ((t & 63) == 0)
        recs[(b << 2) + (t >> 6)] = make_int2(zm, __float_as_int(s));
}

// K2: one wave per row. recs[r*16 .. r*16+16) -> cut; sum full waves below
// cut; re-read only the boundary 256-element micro-chunk.
__global__ __launch_bounds__(256) void bicut_k2(
    const float* __restrict__ out,
    const int* __restrict__ labels,
    const int2* __restrict__ recs,
    float* __restrict__ rowsum) {
    const int lane = threadIdx.x & 63;
    const int wid = threadIdx.x >> 6;
    const int r = (blockIdx.x << 2) + wid;

    const int w = lane & 15;
    const int2 rec = recs[r * 16 + w];  // lanes 16-63 duplicate (max-safe)
    int zm = rec.x;
#pragma unroll
    for (int off = 32; off; off >>= 1) zm = max(zm, __shfl_down(zm, off));
    zm = __shfl(zm, 0);
    const int cut = (zm < 0) ? LROW : zm;

    float s = (lane < 16 && (w + 1) * 256 <= cut) ? __int_as_float(rec.y) : 0.0f;

    if (cut & 255) {  // boundary micro-chunk [mb*256, cut)
        const int mb = cut >> 8;
        const int j0 = (mb << 8) + (lane << 2);  // row-local
        const int e0 = r * LROW + j0;
        const float4* o4 = reinterpret_cast<const float4*>(out);
        const int4* l4 = reinterpret_cast<const int4*>(labels);
        const float4 a = o4[e0 >> 1];
        const float4 c = o4[(e0 >> 1) + 1];
        const int4 lb = l4[e0 >> 2];
        if (j0 + 0 < cut) s += a.y * reward(lb.x, j0);
        if (j0 + 1 < cut) s += a.w * reward(lb.y, j0 + 1);
        if (j0 + 2 < cut) s += c.y * reward(lb.z, j0 + 2);
        if (j0 + 3 < cut) s += c.w * reward(lb.w, j0 + 3);
    }

#pragma unroll
    for (int off = 32; off; off >>= 1) s += __shfl_down(s, off);
    if (lane == 0) rowsum[r] = s;
}

__global__ __launch_bounds__(256) void bicut_final_kernel(
    const float* __restrict__ partial,
    float* __restrict__ loss) {
    const int tid = threadIdx.x;
    const float4* p4 = reinterpret_cast<const float4*>(partial);
    float s = 0.0f;
#pragma unroll
    for (int k = 0; k < BROW / 4 / 256; ++k) {  // 4096 floats = 1024 float4s
        const float4 v = p4[k * 256 + tid];
        s += v.x + v.y + v.z + v.w;
    }
    __shared__ float ss[4];
    const int wid = tid >> 6, lane = tid & 63;
#pragma unroll
    for (int off = 32; off; off >>= 1) s += __shfl_down(s, off);
    if (lane == 0) ss[wid] = s;
    __syncthreads();
    if (tid == 0) loss[0] = (ss[0] + ss[1] + ss[2] + ss[3]) * (1.0f / (float)BROW);
}

extern "C" void kernel_launch(void* const* d_in, const int* in_sizes, int n_in,
                              void* d_out, int out_size, void* d_ws, size_t ws_size,
                              hipStream_t stream) {
    const float* out = (const float*)d_in[0];
    const int* labels = (const int*)d_in[1];
    float* loss = (float*)d_out;
    int2* recs = (int2*)d_ws;                           // 65536 * 8B = 512 KB
    float* rowsum = (float*)((char*)d_ws + (1 << 20));  // 4096 * 4B at +1MB

    bicut_k1<<<(BROW * LROW) / 1024, 256, 0, stream>>>(out, labels, recs);
    bicut_k2<<<BROW / 4, 256, 0, stream>>>(out, labels, recs, rowsum);
    bicut_final_kernel<<<1, 256, 0, stream>>>(rowsum, loss);
}

// Round 14
// 222.411 us; speedup vs baseline: 1.0529x; 1.0529x over previous
//
#include <hip/hip_runtime.h>

// BiCutLoss: output [B,L,2] f32, labels [B,L] i32 -> scalar f32.
// Per row: cut = last j with out1 <= out0 (else L); loss = sum_{j<cut} out1*r1 / B.
// r1 = (label==1) ? -3.6/log2(j+2) : 0.065.
//
// Rounds 3-9: six structures all deliver 2.5-2.8 TB/s reads (writes: 6.9).
// This round: persistent-contiguous K1 (1024 blocks, each walks a contiguous
// 131KB+65KB slab like the fast fill kernel) + nontemporal loads via native
// clang ext_vector_type (HIP float4 is rejected by the builtin).

#define LROW 4096
#define BROW 4096
#define ALPHA_R 0.065f           // alpha * 0.1
#define NCHUNK ((BROW * LROW) / 256)  // 65536 records, one per 256-elem chunk
#define K1_BLOCKS 1024
#define CPB (NCHUNK / K1_BLOCKS)      // 64 chunks per block
#define ITERS (CPB / 4)               // 16 iterations, 4 waves

typedef float f32x4 __attribute__((ext_vector_type(4)));
typedef int i32x4 __attribute__((ext_vector_type(4)));

__device__ __forceinline__ float reward(int lab, int jl) {
    // -3.6/log2(j+2) via v_log_f32 + v_rcp_f32 (rel err ~1e-6 vs 2.8e-3 thr)
    const float pr = -3.6f * __builtin_amdgcn_rcpf(__log2f((float)jl + 2.0f));
    return (lab == 1) ? pr : ALPHA_R;
}

// K1: persistent-contiguous. Block b owns chunks [b*64, b*64+64) = contiguous
// 131KB of output + 65KB of labels. Each wave handles one 256-elem chunk per
// iteration: lane reads 4 elements (2 16B + 1 16B, nontemporal). One
// {zmax, sum} record per chunk. No barriers, no LDS.
__global__ __launch_bounds__(256) void bicut_k1(
    const float* __restrict__ out,
    const int* __restrict__ labels,
    int2* __restrict__ recs) {
    const int wid = threadIdx.x >> 6, lane = threadIdx.x & 63;
    const int cbase = blockIdx.x * CPB + wid;
    const f32x4* o4 = reinterpret_cast<const f32x4*>(out);
    const i32x4* l4 = reinterpret_cast<const i32x4*>(labels);

#pragma unroll 2
    for (int it = 0; it < ITERS; ++it) {
        const int c = cbase + it * 4;               // this wave's chunk
        const int jl = ((c << 8) + (lane << 2)) & (LROW - 1);  // row-local pos
        const f32x4 a = __builtin_nontemporal_load(&o4[(c << 7) + (lane << 1)]);
        const f32x4 d = __builtin_nontemporal_load(&o4[(c << 7) + (lane << 1) + 1]);
        const i32x4 lb = __builtin_nontemporal_load(&l4[(c << 6) + lane]);

        int zm = -1;  // row-local last index with temp==0 (argmax tie -> 0)
        if (!(a.y > a.x)) zm = jl;
        if (!(a.w > a.z)) zm = jl + 1;
        if (!(d.y > d.x)) zm = jl + 2;
        if (!(d.w > d.z)) zm = jl + 3;

        float s = a.y * reward(lb.x, jl)
                + a.w * reward(lb.y, jl + 1)
                + d.y * reward(lb.z, jl + 2)
                + d.w * reward(lb.w, jl + 3);

#pragma unroll
        for (int off = 32; off; off >>= 1) {
            zm = max(zm, __shfl_down(zm, off));
            s += __shfl_down(s, off);
        }
        if (lane == 0) recs[c] = make_int2(zm, __float_as_int(s));
    }
}

// K2: one wave per row. recs[r*16 .. r*16+16) -> cut; sum full chunks below
// cut; re-read only the boundary 256-element micro-chunk. (Unchanged, r9.)
__global__ __launch_bounds__(256) void bicut_k2(
    const float* __restrict__ out,
    const int* __restrict__ labels,
    const int2* __restrict__ recs,
    float* __restrict__ rowsum) {
    const int lane = threadIdx.x & 63;
    const int wid = threadIdx.x >> 6;
    const int r = (blockIdx.x << 2) + wid;

    const int w = lane & 15;
    const int2 rec = recs[r * 16 + w];  // lanes 16-63 duplicate (max-safe)
    int zm = rec.x;
#pragma unroll
    for (int off = 32; off; off >>= 1) zm = max(zm, __shfl_down(zm, off));
    zm = __shfl(zm, 0);
    const int cut = (zm < 0) ? LROW : zm;

    float s = (lane < 16 && (w + 1) * 256 <= cut) ? __int_as_float(rec.y) : 0.0f;

    if (cut & 255) {  // boundary micro-chunk [mb*256, cut)
        const int mb = cut >> 8;
        const int j0 = (mb << 8) + (lane << 2);  // row-local
        const int e0 = r * LROW + j0;
        const float4* o4 = reinterpret_cast<const float4*>(out);
        const int4* l4 = reinterpret_cast<const int4*>(labels);
        const float4 a = o4[e0 >> 1];
        const float4 d = o4[(e0 >> 1) + 1];
        const int4 lb = l4[e0 >> 2];
        if (j0 + 0 < cut) s += a.y * reward(lb.x, j0);
        if (j0 + 1 < cut) s += a.w * reward(lb.y, j0 + 1);
        if (j0 + 2 < cut) s += d.y * reward(lb.z, j0 + 2);
        if (j0 + 3 < cut) s += d.w * reward(lb.w, j0 + 3);
    }

#pragma unroll
    for (int off = 32; off; off >>= 1) s += __shfl_down(s, off);
    if (lane == 0) rowsum[r] = s;
}

__global__ __launch_bounds__(256) void bicut_final_kernel(
    const float* __restrict__ partial,
    float* __restrict__ loss) {
    const int tid = threadIdx.x;
    const float4* p4 = reinterpret_cast<const float4*>(partial);
    float s = 0.0f;
#pragma unroll
    for (int k = 0; k < BROW / 4 / 256; ++k) {  // 4096 floats = 1024 float4s
        const float4 v = p4[k * 256 + tid];
        s += v.x + v.y + v.z + v.w;
    }
    __shared__ float ss[4];
    const int wid = tid >> 6, lane = tid & 63;
#pragma unroll
    for (int off = 32; off; off >>= 1) s += __shfl_down(s, off);
    if (lane == 0) ss[wid] = s;
    __syncthreads();
    if (tid == 0) loss[0] = (ss[0] + ss[1] + ss[2] + ss[3]) * (1.0f / (float)BROW);
}

extern "C" void kernel_launch(void* const* d_in, const int* in_sizes, int n_in,
                              void* d_out, int out_size, void* d_ws, size_t ws_size,
                              hipStream_t stream) {
    const float* out = (const float*)d_in[0];
    const int* labels = (const int*)d_in[1];
    float* loss = (float*)d_out;
    int2* recs = (int2*)d_ws;                           // 65536 * 8B = 512 KB
    float* rowsum = (float*)((char*)d_ws + (1 << 20));  // 4096 * 4B at +1MB

    bicut_k1<<<K1_BLOCKS, 256, 0, stream>>>(out, labels, recs);
    bicut_k2<<<BROW / 4, 256, 0, stream>>>(out, labels, recs, rowsum);
    bicut_final_kernel<<<1, 256, 0, stream>>>(rowsum, loss);
}